// Round 19
// baseline (152.530 us; speedup 1.0000x reference)
//
#include <hip/hip_runtime.h>
#include <hip/hip_fp16.h>
#include <hip/hip_cooperative_groups.h>
#include <math.h>

namespace cg = cooperative_groups;

#define NK    125    // KSIZE^3
#define HID   8
#define BSH   7      // 128 dst-nodes per bucket (R19: 2 blocks/CU LDS-limited -> coop fits)
#define BKT   128
#define CAP   5120   // bucket capacity; mean 4092, std ~64 -> +16 sigma
#define MAXNB 1024
#define CHUNK 6272   // edges per partition block -> exactly 256 blocks at E=1.6M
#define PTHR  1024   // partition block threads (16 waves: hide pass-3 latency)
#define WS    12     // sW row stride (floats): 16B-aligned, bank-spread
#define FQ    (1.f / 65536.f)

__device__ __forceinline__ float eluf(float v) {
    return v > 0.f ? v : expf(v) - 1.f;
}

__device__ __forceinline__ float dq(int q) {   // 16-bit fixed -> [0,1)
    return ((float)q + 0.5f) * FQ;
}

// ======================= bucketed (fast) path =======================

// cursor deliberately UNPADDED: packed counters share lines and the memory-side
// atomic unit coalesces same-line ops (R4 53us/52.9MB vs padded R6 68us/64MB).
__global__ __launch_bounds__(256) void init_cursor(int* __restrict__ cursor, int NB) {
    int b = blockIdx.x * 256 + threadIdx.x;
    if (b < NB) cursor[b] = b * CAP;
}

// Partition: 4B/edge LDS stage {src|nl<<16|b<<23}; edge id recovered as
// e = e0 + perm[o]. CHUNK 6272 -> exactly 256 blocks (1/CU): R15 confirmed
// partition is block-critical-path-bound. BSH=7 -> ~100K reservation atomics.
// Payload: 10B/edge SoA pay8 {src|kb<<16|nl<<23, q0|q1<<16} + payf2 (u16).
__global__ __launch_bounds__(PTHR) void partition_edges(
    const int* __restrict__ src, const int* __restrict__ dst,
    const float* __restrict__ pseudo,
    int* __restrict__ cursor, int2* __restrict__ pay8,
    unsigned short* __restrict__ payf2,
    int E, int NB)
{
    __shared__ int stage[CHUNK];             // 25.1 KB {src|nl<<16|b<<23}
    __shared__ unsigned short perm[CHUNK];   // 12.5 KB (output slot -> staged idx)
    __shared__ int s_off[MAXNB + 1];         // 4.1 KB (hist -> prefix -> claim)
    __shared__ int s_gmo[MAXNB];             // 4 KB (global base minus local off)

    int e0  = blockIdx.x * CHUNK;
    int cnt = min(CHUNK, E - e0);

    for (int b = threadIdx.x; b < NB; b += PTHR) s_off[b] = 0;
    __syncthreads();

    // pass 1: coalesced src/dst read; histogram buckets
    for (int i = threadIdx.x; i < cnt; i += PTHR) {
        int e = e0 + i;
        int d = dst[e];
        int b = d >> BSH;
        stage[i] = src[e] | ((d & (BKT - 1)) << 16) | (b << 23);
        atomicAdd(&s_off[b], 1);
    }
    __syncthreads();

    // exclusive scan of s_off[0..NB) by wave 0 (lane-chunked + shfl scan)
    if (threadIdx.x < 64) {
        int per = (NB + 63) >> 6;
        int lo = threadIdx.x * per, hi = min(lo + per, NB);
        int sum = 0;
        for (int b = lo; b < hi; ++b) { int v = s_off[b]; s_off[b] = sum; sum += v; }
        int incl = sum;
        for (int d2 = 1; d2 < 64; d2 <<= 1) {
            int u = __shfl_up(incl, d2, 64);
            if ((int)threadIdx.x >= d2) incl += u;
        }
        int basep = incl - sum;
        for (int b = lo; b < hi; ++b) s_off[b] += basep;
        if (threadIdx.x == 63) s_off[NB] = incl;   // == cnt
    }
    __syncthreads();

    // reserve global runs (one packed atomic per nonempty bucket)
    for (int b = threadIdx.x; b < NB; b += PTHR) {
        int c = s_off[b + 1] - s_off[b];
        int g = c ? atomicAdd(&cursor[b], c) : 0;
        s_gmo[b] = g - s_off[b];
    }
    __syncthreads();

    // pass 2: claim per-edge ranks (destroys s_off; s_gmo already captured)
    for (int i = threadIdx.x; i < cnt; i += PTHR) {
        unsigned ux = (unsigned)stage[i];
        int r = atomicAdd(&s_off[ux >> 23], 1);
        perm[r] = (unsigned short)i;
    }
    __syncthreads();

    // pass 3: output-ordered write; e recovered from perm; pseudo read +
    // kb/frac quantize here (pseudo stream touched exactly once)
    for (int o = threadIdx.x; o < cnt; o += PTHR) {
        int i = perm[o];
        unsigned ux = (unsigned)stage[i];
        int e  = e0 + i;
        int sidx = ux & 0xFFFF;
        int nl   = (ux >> 16) & (BKT - 1);
        int b    = ux >> 23;
        float p0 = pseudo[3 * e + 0] * 4.f;
        float p1 = pseudo[3 * e + 1] * 4.f;
        float p2 = pseudo[3 * e + 2] * 4.f;
        int i0 = min(max((int)floorf(p0), 0), 3);
        int i1 = min(max((int)floorf(p1), 0), 3);
        int i2 = min(max((int)floorf(p2), 0), 3);
        float f0 = p0 - (float)i0, f1 = p1 - (float)i1, f2 = p2 - (float)i2;
        int kb = i0 + 5 * i1 + 25 * i2;
        int q0 = min((int)(f0 * 65536.f), 65535);
        int q1 = min((int)(f1 * 65536.f), 65535);
        int q2 = min((int)(f2 * 65536.f), 65535);
        int g = s_gmo[b] + o;
        if (g < (b + 1) * CAP) {             // memory-safety clamp
            pay8[g]  = make_int2(sidx | (kb << 16) | (nl << 23), q0 | (q1 << 16));
            payf2[g] = (unsigned short)q2;
        }
    }
}

// 128-bin exclusive scan by wave 0 (2 bins/lane + shfl scan).
__device__ __forceinline__ void scan128(int* hist, int* off, int* cur, int tid) {
    if (tid < 64) {
        int lo = tid * 2;
        int v0 = hist[lo], v1 = hist[lo + 1];
        int sum = v0 + v1;
        int incl = sum;
        for (int d = 1; d < 64; d <<= 1) {
            int u = __shfl_up(incl, d, 64);
            if (tid >= d) incl += u;
        }
        int basep = incl - sum;
        off[lo] = basep;       off[lo + 1] = basep + v0;
        cur[lo] = basep;       cur[lo + 1] = basep + v0;
        if (tid == 63) off[BKT] = incl;
    }
}

// Fused layers (cooperative): one block per 128-node bucket. Phase 1 = layer1
// (stage, in-LDS counting sort, compute, h as f16) — NO payload persist;
// grid.sync(); Phase 2 = layer2 on the SAME bucket from LDS. Erases the 32MB
// sorted-payload relay. LDS ~69KB -> exactly 2 blocks/CU -> 512 >= 391 blocks
// co-resident (the R18 VGPR-occupancy trap at BSH=6 is avoided).
__global__ __launch_bounds__(512) void layers_fused(
    const int2* __restrict__ pay8, const unsigned short* __restrict__ payf2,
    const int* __restrict__ cursor,
    const float* __restrict__ x,
    const float* __restrict__ W1, const float* __restrict__ root1,
    const float* __restrict__ bias1,
    const float* __restrict__ W2, const float* __restrict__ root2,
    const float* __restrict__ bias2,
    __half* __restrict__ h, float* __restrict__ out, int N)
{
    cg::grid_group grid = cg::this_grid();

    __shared__ float sW[NK * WS];            // 6 KB (W1, then W2 after sync)
    __shared__ int2 stage[CAP];              // 40 KB
    __shared__ unsigned short stf2[CAP];     // 10 KB
    __shared__ unsigned short perm[CAP];     // 10 KB
    __shared__ int hist[BKT];
    __shared__ int off[BKT + 1];
    __shared__ int cur[BKT];

    for (int i = threadIdx.x; i < NK * HID; i += 512)
        sW[(i >> 3) * WS + (i & 7)] = W1[i];
    for (int b = threadIdx.x; b < BKT; b += 512) hist[b] = 0;
    __syncthreads();

    int bkt  = blockIdx.x;
    int base = bkt * CAP;
    int cnt  = min(cursor[bkt] - base, CAP);

    for (int i = threadIdx.x; i < cnt; i += 512) {
        int2 pl = pay8[base + i];
        stage[i] = pl;
        stf2[i]  = payf2[base + i];
        atomicAdd(&hist[(pl.x >> 23) & (BKT - 1)], 1);
    }
    __syncthreads();

    scan128(hist, off, cur, threadIdx.x);
    __syncthreads();

    for (int i = threadIdx.x; i < cnt; i += 512) {
        int nl = (stage[i].x >> 23) & (BKT - 1);
        int pos = atomicAdd(&cur[nl], 1);
        perm[pos] = (unsigned short)i;
    }
    __syncthreads();

    int g8 = threadIdx.x >> 3;               // 64 groups x 8 lanes; 2 nodes/group
    int j  = threadIdx.x & 7;

    // ---- phase 1: layer1 compute -> h (f16) ----
#pragma unroll 1
    for (int half = 0; half < 2; ++half) {
        int nl = half * 64 + g8;
        int s = off[nl], e = off[nl + 1];
        int n = (bkt << BSH) + nl;

        float4 aclo = make_float4(0.f, 0.f, 0.f, 0.f);
        float4 achi = make_float4(0.f, 0.f, 0.f, 0.f);

        for (int i = s + j; i < e; i += 8) {
            int pi = perm[i];
            int2 pl = stage[pi];
            int packed = pl.x;
            float f0 = dq(pl.y & 0xFFFF);
            float f1 = dq((int)((unsigned)pl.y >> 16));
            float f2 = dq(stf2[pi]);
            int sidx = packed & 0xFFFF;
            int kb   = (packed >> 16) & 0x7F;
            float xj = x[sidx];
#pragma unroll
            for (int b = 0; b < 8; ++b) {
                int kidx = kb + (b & 1) + ((b >> 1) & 1) * 5 + ((b >> 2) & 1) * 25;
                float basis = ((b & 1) ? f0 : 1.f - f0)
                            * ((b & 2) ? f1 : 1.f - f1)
                            * ((b & 4) ? f2 : 1.f - f2);
                float w = xj * basis;
                float4 wlo = *(const float4*)&sW[kidx * WS];
                float4 whi = *(const float4*)&sW[kidx * WS + 4];
                aclo.x += w * wlo.x; aclo.y += w * wlo.y;
                aclo.z += w * wlo.z; aclo.w += w * wlo.w;
                achi.x += w * whi.x; achi.y += w * whi.y;
                achi.z += w * whi.z; achi.w += w * whi.w;
            }
        }

        float acc[HID] = {aclo.x, aclo.y, aclo.z, aclo.w, achi.x, achi.y, achi.z, achi.w};
#pragma unroll
        for (int m = 1; m < 8; m <<= 1)
#pragma unroll
            for (int o = 0; o < HID; ++o)
                acc[o] += __shfl_xor(acc[o], m, 64);

        if (n < N) {
            float v = acc[j] + x[n] * root1[j] + bias1[j];
            h[(size_t)n * HID + j] = __float2half(eluf(v));
        }
    }

    __threadfence();      // make h visible device-wide before the grid barrier
    grid.sync();

    // ---- phase 2: layer2 on the same bucket; stage/perm/off still in LDS ----
    for (int i = threadIdx.x; i < NK * HID; i += 512)
        sW[(i >> 3) * WS + (i & 7)] = W2[i];
    __syncthreads();

#pragma unroll 1
    for (int half = 0; half < 2; ++half) {
        int nl = half * 64 + g8;
        int s = off[nl], e = off[nl + 1];
        int n = (bkt << BSH) + nl;

        float msg = 0.f;
        for (int i = s + j; i < e; i += 8) {
            int pi = perm[i];
            int2 pl = stage[pi];
            int packed = pl.x;
            float f0 = dq(pl.y & 0xFFFF);
            float f1 = dq((int)((unsigned)pl.y >> 16));
            float f2 = dq(stf2[pi]);
            int sidx = packed & 0xFFFF;
            int kb   = (packed >> 16) & 0x7F;
            uint4 hw = *(const uint4*)(h + (size_t)sidx * HID);  // 16B: 8 halves
            float2 h01 = __half22float2(*(__half2*)&hw.x);
            float2 h23 = __half22float2(*(__half2*)&hw.y);
            float2 h45 = __half22float2(*(__half2*)&hw.z);
            float2 h67 = __half22float2(*(__half2*)&hw.w);
#pragma unroll
            for (int b = 0; b < 8; ++b) {
                int kidx = kb + (b & 1) + ((b >> 1) & 1) * 5 + ((b >> 2) & 1) * 25;
                float basis = ((b & 1) ? f0 : 1.f - f0)
                            * ((b & 2) ? f1 : 1.f - f1)
                            * ((b & 4) ? f2 : 1.f - f2);
                float4 wlo = *(const float4*)&sW[kidx * WS];
                float4 whi = *(const float4*)&sW[kidx * WS + 4];
                float dot = h01.x * wlo.x + h01.y * wlo.y + h23.x * wlo.z + h23.y * wlo.w
                          + h45.x * whi.x + h45.y * whi.y + h67.x * whi.z + h67.y * whi.w;
                msg += basis * dot;
            }
        }

        if (n < N) msg += __half2float(h[(size_t)n * HID + j]) * root2[j];

#pragma unroll
        for (int m = 1; m < 8; m <<= 1)
            msg += __shfl_xor(msg, m, 64);

        if (j == 0 && n < N)
            out[n] = eluf(msg + bias2[0]);
    }
}

// ----- non-cooperative fallback: two-kernel layers (BSH=7 geometry) -----

__global__ __launch_bounds__(512) void layer1_fused(
    int2* __restrict__ pay8, unsigned short* __restrict__ payf2,
    const int* __restrict__ cursor,
    const float* __restrict__ x, const float* __restrict__ W1,
    const float* __restrict__ root1, const float* __restrict__ bias1,
    __half* __restrict__ h, int* __restrict__ ns, int* __restrict__ ne, int N)
{
    __shared__ float sW[NK * WS];
    __shared__ int2 stage[CAP];
    __shared__ unsigned short stf2[CAP];
    __shared__ unsigned short perm[CAP];
    __shared__ int hist[BKT];
    __shared__ int off[BKT + 1];
    __shared__ int cur[BKT];

    for (int i = threadIdx.x; i < NK * HID; i += 512)
        sW[(i >> 3) * WS + (i & 7)] = W1[i];
    for (int b = threadIdx.x; b < BKT; b += 512) hist[b] = 0;
    __syncthreads();

    int bkt  = blockIdx.x;
    int base = bkt * CAP;
    int cnt  = min(cursor[bkt] - base, CAP);

    for (int i = threadIdx.x; i < cnt; i += 512) {
        int2 pl = pay8[base + i];
        stage[i] = pl;
        stf2[i]  = payf2[base + i];
        atomicAdd(&hist[(pl.x >> 23) & (BKT - 1)], 1);
    }
    __syncthreads();

    scan128(hist, off, cur, threadIdx.x);
    __syncthreads();

    for (int i = threadIdx.x; i < cnt; i += 512) {
        int nl = (stage[i].x >> 23) & (BKT - 1);
        int pos = atomicAdd(&cur[nl], 1);
        perm[pos] = (unsigned short)i;
    }
    __syncthreads();

    // persist sorted payload (coalesced) + per-node bounds for layer2
    for (int i = threadIdx.x; i < cnt; i += 512) {
        int pi = perm[i];
        pay8[base + i]  = stage[pi];
        payf2[base + i] = stf2[pi];
    }
    for (int b = threadIdx.x; b < BKT; b += 512) {
        int n = (bkt << BSH) + b;
        if (n < N) {
            ns[n] = base + off[b];
            ne[n] = base + off[b + 1];
        }
    }

    int g8 = threadIdx.x >> 3;
    int j  = threadIdx.x & 7;

#pragma unroll 1
    for (int half = 0; half < 2; ++half) {
        int nl = half * 64 + g8;
        int s = off[nl], e = off[nl + 1];
        int n = (bkt << BSH) + nl;

        float4 aclo = make_float4(0.f, 0.f, 0.f, 0.f);
        float4 achi = make_float4(0.f, 0.f, 0.f, 0.f);

        for (int i = s + j; i < e; i += 8) {
            int pi = perm[i];
            int2 pl = stage[pi];
            int packed = pl.x;
            float f0 = dq(pl.y & 0xFFFF);
            float f1 = dq((int)((unsigned)pl.y >> 16));
            float f2 = dq(stf2[pi]);
            int sidx = packed & 0xFFFF;
            int kb   = (packed >> 16) & 0x7F;
            float xj = x[sidx];
#pragma unroll
            for (int b = 0; b < 8; ++b) {
                int kidx = kb + (b & 1) + ((b >> 1) & 1) * 5 + ((b >> 2) & 1) * 25;
                float basis = ((b & 1) ? f0 : 1.f - f0)
                            * ((b & 2) ? f1 : 1.f - f1)
                            * ((b & 4) ? f2 : 1.f - f2);
                float w = xj * basis;
                float4 wlo = *(const float4*)&sW[kidx * WS];
                float4 whi = *(const float4*)&sW[kidx * WS + 4];
                aclo.x += w * wlo.x; aclo.y += w * wlo.y;
                aclo.z += w * wlo.z; aclo.w += w * wlo.w;
                achi.x += w * whi.x; achi.y += w * whi.y;
                achi.z += w * whi.z; achi.w += w * whi.w;
            }
        }

        float acc[HID] = {aclo.x, aclo.y, aclo.z, aclo.w, achi.x, achi.y, achi.z, achi.w};
#pragma unroll
        for (int m = 1; m < 8; m <<= 1)
#pragma unroll
            for (int o = 0; o < HID; ++o)
                acc[o] += __shfl_xor(acc[o], m, 64);

        if (n < N) {
            float v = acc[j] + x[n] * root1[j] + bias1[j];
            h[(size_t)n * HID + j] = __float2half(eluf(v));
        }
    }
}

__global__ __launch_bounds__(256) void layer2_csr(
    const int2* __restrict__ pay8, const unsigned short* __restrict__ payf2,
    const int* __restrict__ ns, const int* __restrict__ ne,
    const __half* __restrict__ h, const float* __restrict__ W2,
    const float* __restrict__ root2, const float* __restrict__ bias2,
    float* __restrict__ out, int N)
{
    __shared__ float sW[NK * WS];
    for (int i = threadIdx.x; i < NK * HID; i += 256)
        sW[(i >> 3) * WS + (i & 7)] = W2[i];
    __syncthreads();

    int n = blockIdx.x * 32 + (threadIdx.x >> 3);
    int j = threadIdx.x & 7;
    int s = 0, e = 0;
    if (n < N) { s = ns[n]; e = ne[n]; }

    float msg = 0.f;
    for (int i = s + j; i < e; i += 8) {
        int2 pl = pay8[i];
        int packed = pl.x;
        float f0 = dq(pl.y & 0xFFFF);
        float f1 = dq((int)((unsigned)pl.y >> 16));
        float f2 = dq(payf2[i]);
        int sidx = packed & 0xFFFF;
        int kb   = (packed >> 16) & 0x7F;
        uint4 hw = *(const uint4*)(h + (size_t)sidx * HID);
        float2 h01 = __half22float2(*(__half2*)&hw.x);
        float2 h23 = __half22float2(*(__half2*)&hw.y);
        float2 h45 = __half22float2(*(__half2*)&hw.z);
        float2 h67 = __half22float2(*(__half2*)&hw.w);
#pragma unroll
        for (int b = 0; b < 8; ++b) {
            int kidx = kb + (b & 1) + ((b >> 1) & 1) * 5 + ((b >> 2) & 1) * 25;
            float basis = ((b & 1) ? f0 : 1.f - f0)
                        * ((b & 2) ? f1 : 1.f - f1)
                        * ((b & 4) ? f2 : 1.f - f2);
            float4 wlo = *(const float4*)&sW[kidx * WS];
            float4 whi = *(const float4*)&sW[kidx * WS + 4];
            float dot = h01.x * wlo.x + h01.y * wlo.y + h23.x * wlo.z + h23.y * wlo.w
                      + h45.x * whi.x + h45.y * whi.y + h67.x * whi.z + h67.y * whi.w;
            msg += basis * dot;
        }
    }

    if (n < N) msg += __half2float(h[(size_t)n * HID + j]) * root2[j];

#pragma unroll
    for (int m = 1; m < 8; m <<= 1)
        msg += __shfl_xor(msg, m, 64);

    if (j == 0 && n < N)
        out[n] = eluf(msg + bias2[0]);
}

// ======================= fallback (atomic) path =======================

__global__ __launch_bounds__(256) void spline_edge1(
    const int* __restrict__ src, const int* __restrict__ dst,
    const float* __restrict__ pseudo, const float* __restrict__ x,
    const float* __restrict__ W1, float* __restrict__ hacc, int E)
{
    __shared__ float sW[HID * NK];
    for (int i = threadIdx.x; i < HID * NK; i += blockDim.x) {
        int k = i >> 3, o = i & 7;
        sW[o * NK + k] = W1[i];
    }
    __syncthreads();
    int e = blockIdx.x * blockDim.x + threadIdx.x;
    if (e >= E) return;
    float p0 = pseudo[3 * e + 0] * 4.f, p1 = pseudo[3 * e + 1] * 4.f, p2 = pseudo[3 * e + 2] * 4.f;
    int i0 = min(max((int)floorf(p0), 0), 3);
    int i1 = min(max((int)floorf(p1), 0), 3);
    int i2 = min(max((int)floorf(p2), 0), 3);
    float f0 = p0 - i0, f1 = p1 - i1, f2 = p2 - i2;
    int kbase = i0 + 5 * i1 + 25 * i2;
    float xj = x[src[e]];
    float acc[HID];
#pragma unroll
    for (int o = 0; o < HID; ++o) acc[o] = 0.f;
#pragma unroll
    for (int b = 0; b < 8; ++b) {
        int kidx = kbase + (b & 1) + ((b >> 1) & 1) * 5 + ((b >> 2) & 1) * 25;
        float basis = ((b & 1) ? f0 : 1.f - f0) * ((b & 2) ? f1 : 1.f - f1) * ((b & 4) ? f2 : 1.f - f2);
#pragma unroll
        for (int o = 0; o < HID; ++o) acc[o] += basis * sW[o * NK + kidx];
    }
    float* hp = hacc + (size_t)dst[e] * HID;
#pragma unroll
    for (int o = 0; o < HID; ++o) atomicAdd(hp + o, xj * acc[o]);
}

__global__ __launch_bounds__(256) void node1(
    float* __restrict__ h, const float* __restrict__ x,
    const float* __restrict__ root1, const float* __restrict__ bias1, int N)
{
    int t = blockIdx.x * blockDim.x + threadIdx.x;
    if (t >= N * HID) return;
    int n = t >> 3, o = t & 7;
    h[t] = eluf(h[t] + x[n] * root1[o] + bias1[o]);
}

__global__ __launch_bounds__(256) void spline_edge2(
    const int* __restrict__ src, const int* __restrict__ dst,
    const float* __restrict__ pseudo, const float* __restrict__ h,
    const float* __restrict__ W2, float* __restrict__ oacc, int E)
{
    __shared__ float sW[HID * NK];
    for (int idx = threadIdx.x; idx < HID * NK; idx += blockDim.x) {
        int k = idx >> 3, i = idx & 7;
        sW[i * NK + k] = W2[idx];
    }
    __syncthreads();
    int e = blockIdx.x * blockDim.x + threadIdx.x;
    if (e >= E) return;
    float p0 = pseudo[3 * e + 0] * 4.f, p1 = pseudo[3 * e + 1] * 4.f, p2 = pseudo[3 * e + 2] * 4.f;
    int i0 = min(max((int)floorf(p0), 0), 3);
    int i1 = min(max((int)floorf(p1), 0), 3);
    int i2 = min(max((int)floorf(p2), 0), 3);
    float f0 = p0 - i0, f1 = p1 - i1, f2 = p2 - i2;
    int kbase = i0 + 5 * i1 + 25 * i2;
    const float4* hp4 = (const float4*)(h + (size_t)src[e] * HID);
    float4 ha = hp4[0], hb = hp4[1];
    float hj[HID] = {ha.x, ha.y, ha.z, ha.w, hb.x, hb.y, hb.z, hb.w};
    float msg = 0.f;
#pragma unroll
    for (int b = 0; b < 8; ++b) {
        int kidx = kbase + (b & 1) + ((b >> 1) & 1) * 5 + ((b >> 2) & 1) * 25;
        float basis = ((b & 1) ? f0 : 1.f - f0) * ((b & 2) ? f1 : 1.f - f1) * ((b & 4) ? f2 : 1.f - f2);
        float dot = 0.f;
#pragma unroll
        for (int i = 0; i < HID; ++i) dot += hj[i] * sW[i * NK + kidx];
        msg += basis * dot;
    }
    atomicAdd(&oacc[dst[e]], msg);
}

__global__ __launch_bounds__(256) void node2(
    const float* __restrict__ oacc, const float* __restrict__ h,
    const float* __restrict__ root2, const float* __restrict__ bias2,
    float* __restrict__ out, int N)
{
    int n = blockIdx.x * blockDim.x + threadIdx.x;
    if (n >= N) return;
    float v = oacc[n] + bias2[0];
#pragma unroll
    for (int i = 0; i < HID; ++i) v += h[(size_t)n * HID + i] * root2[i];
    out[n] = eluf(v);
}

// ======================= launch =======================

extern "C" void kernel_launch(void* const* d_in, const int* in_sizes, int n_in,
                              void* d_out, int out_size, void* d_ws, size_t ws_size,
                              hipStream_t stream) {
    const float* x      = (const float*)d_in[0];
    const int*   ei     = (const int*)d_in[1];
    const float* pseudo = (const float*)d_in[2];
    const float* W1     = (const float*)d_in[3];
    const float* root1  = (const float*)d_in[4];
    const float* bias1  = (const float*)d_in[5];
    const float* W2     = (const float*)d_in[6];
    const float* root2  = (const float*)d_in[7];
    const float* bias2  = (const float*)d_in[8];

    int N = in_sizes[0];
    int E = in_sizes[1] / 2;
    const int* src = ei;
    const int* dst = ei + E;

    int NB = (N + BKT - 1) >> BSH;
    size_t pay8_bytes  = (size_t)NB * CAP * sizeof(int2);
    size_t payf2_bytes = (size_t)NB * CAP * sizeof(unsigned short);
    size_t h_bytes     = ((size_t)N * HID * sizeof(__half) + 15) & ~(size_t)15;
    size_t cursor_bytes = (size_t)NB * sizeof(int);
    size_t nsne_bytes  = (size_t)N * sizeof(int);
    size_t need = pay8_bytes + payf2_bytes + h_bytes + cursor_bytes + 2 * nsne_bytes + 64;

    if (NB <= MAXNB && N <= 65536 && E < (1 << 24) && ws_size >= need) {
        char* p = (char*)d_ws;
        int2*  pay8   = (int2*)p;                  p += pay8_bytes;
        unsigned short* payf2 = (unsigned short*)p; p += payf2_bytes;
        __half* h     = (__half*)p;                p += h_bytes;
        int*   cursor = (int*)p;                   p += cursor_bytes;
        int*   ns     = (int*)p;                   p += nsne_bytes;
        int*   ne     = (int*)p;

        init_cursor<<<(NB + 255) / 256, 256, 0, stream>>>(cursor, NB);
        int pblocks = (E + CHUNK - 1) / CHUNK;
        partition_edges<<<pblocks, PTHR, 0, stream>>>(src, dst, pseudo, cursor, pay8, payf2, E, NB);

        int coopAttr = 0, dev = 0, numCU = 0, maxb = 0;
        hipGetDevice(&dev);
        hipDeviceGetAttribute(&coopAttr, hipDeviceAttributeCooperativeLaunch, dev);
        hipDeviceGetAttribute(&numCU, hipDeviceAttributeMultiprocessorCount, dev);
        hipError_t occ = hipOccupancyMaxActiveBlocksPerMultiprocessor(
            &maxb, (const void*)layers_fused, 512, 0);

        if (coopAttr && occ == hipSuccess && (long)maxb * numCU >= NB) {
            float* outp = (float*)d_out;
            void* args[] = {(void*)&pay8, (void*)&payf2, (void*)&cursor,
                            (void*)&x, (void*)&W1, (void*)&root1, (void*)&bias1,
                            (void*)&W2, (void*)&root2, (void*)&bias2,
                            (void*)&h, (void*)&outp, (void*)&N};
            hipLaunchCooperativeKernel((const void*)layers_fused, dim3(NB), dim3(512),
                                       args, 0, stream);
        } else {
            layer1_fused<<<NB, 512, 0, stream>>>(pay8, payf2, cursor, x, W1, root1, bias1, h, ns, ne, N);
            layer2_csr<<<(N + 31) / 32, 256, 0, stream>>>(pay8, payf2, ns, ne, h, W2, root2, bias2, (float*)d_out, N);
        }
    } else {
        float* h    = (float*)d_ws;
        float* oacc = h + (size_t)N * HID;
        hipMemsetAsync(d_ws, 0, (size_t)(N * HID + N) * sizeof(float), stream);
        int eg = (E + 255) / 256;
        spline_edge1<<<eg, 256, 0, stream>>>(src, dst, pseudo, x, W1, h, E);
        node1<<<(N * HID + 255) / 256, 256, 0, stream>>>(h, x, root1, bias1, N);
        spline_edge2<<<eg, 256, 0, stream>>>(src, dst, pseudo, h, W2, oacc, E);
        node2<<<(N + 255) / 256, 256, 0, stream>>>(oacc, h, root2, bias2, (float*)d_out, N);
    }
}

// Round 20
// 149.173 us; speedup vs baseline: 1.0225x; 1.0225x over previous
//
#include <hip/hip_runtime.h>
#include <hip/hip_fp16.h>
#include <math.h>

#define NK    125    // KSIZE^3
#define HID   8
#define BSH   6      // 64 dst-nodes per bucket
#define BKT   64
#define CAP   2560   // bucket capacity; mean 2046, std ~45 -> +11 sigma
#define MAXNB 1024
#define CHUNK 6272   // edges per partition block -> exactly 256 blocks at E=1.6M
#define PTHR  1024   // partition block threads (16 waves: hide pass-3 latency)
#define WS    12     // sW row stride (floats): 16B-aligned, bank-spread
#define FQ    (1.f / 65536.f)

__device__ __forceinline__ float eluf(float v) {
    return v > 0.f ? v : expf(v) - 1.f;
}

__device__ __forceinline__ float dq(int q) {   // 16-bit fixed -> [0,1)
    return ((float)q + 0.5f) * FQ;
}

// ======================= bucketed (fast) path =======================

// cursor deliberately UNPADDED: packed counters share lines and the memory-side
// atomic unit coalesces same-line ops (R4 53us/52.9MB vs padded R6 68us/64MB).
__global__ __launch_bounds__(256) void init_cursor(int* __restrict__ cursor, int NB) {
    int b = blockIdx.x * 256 + threadIdx.x;
    if (b < NB) cursor[b] = b * CAP;
}

// Partition: 4B/edge LDS stage {src|nl<<16|b<<22}; edge id recovered as
// e = e0 + perm[o]. CHUNK 6272 -> exactly 256 blocks (1/CU, no tail): R15
// confirmed partition is block-critical-path-bound. PTHR 1024 hides latency.
// Payload: 10B/edge SoA pay8 {src|kb<<16|nl<<23, q0|q1<<16} + payf2 (u16).
__global__ __launch_bounds__(PTHR) void partition_edges(
    const int* __restrict__ src, const int* __restrict__ dst,
    const float* __restrict__ pseudo,
    int* __restrict__ cursor, int2* __restrict__ pay8,
    unsigned short* __restrict__ payf2,
    int E, int NB)
{
    __shared__ int stage[CHUNK];             // 25.1 KB {src|nl<<16|b<<22}
    __shared__ unsigned short perm[CHUNK];   // 12.5 KB (output slot -> staged idx)
    __shared__ int s_off[MAXNB + 1];         // 4.1 KB (hist -> prefix -> claim)
    __shared__ int s_gmo[MAXNB];             // 4 KB (global base minus local off)

    int e0  = blockIdx.x * CHUNK;
    int cnt = min(CHUNK, E - e0);

    for (int b = threadIdx.x; b < NB; b += PTHR) s_off[b] = 0;
    __syncthreads();

    // pass 1: coalesced src/dst read; histogram buckets
    for (int i = threadIdx.x; i < cnt; i += PTHR) {
        int e = e0 + i;
        int d = dst[e];
        int b = d >> BSH;
        stage[i] = src[e] | ((d & (BKT - 1)) << 16) | (b << 22);
        atomicAdd(&s_off[b], 1);
    }
    __syncthreads();

    // exclusive scan of s_off[0..NB) by wave 0 (lane-chunked + shfl scan)
    if (threadIdx.x < 64) {
        int per = (NB + 63) >> 6;
        int lo = threadIdx.x * per, hi = min(lo + per, NB);
        int sum = 0;
        for (int b = lo; b < hi; ++b) { int v = s_off[b]; s_off[b] = sum; sum += v; }
        int incl = sum;
        for (int d2 = 1; d2 < 64; d2 <<= 1) {
            int u = __shfl_up(incl, d2, 64);
            if ((int)threadIdx.x >= d2) incl += u;
        }
        int basep = incl - sum;
        for (int b = lo; b < hi; ++b) s_off[b] += basep;
        if (threadIdx.x == 63) s_off[NB] = incl;   // == cnt
    }
    __syncthreads();

    // reserve global runs (one packed atomic per nonempty bucket)
    for (int b = threadIdx.x; b < NB; b += PTHR) {
        int c = s_off[b + 1] - s_off[b];
        int g = c ? atomicAdd(&cursor[b], c) : 0;
        s_gmo[b] = g - s_off[b];
    }
    __syncthreads();

    // pass 2: claim per-edge ranks (destroys s_off; s_gmo already captured)
    for (int i = threadIdx.x; i < cnt; i += PTHR) {
        unsigned ux = (unsigned)stage[i];
        int r = atomicAdd(&s_off[ux >> 22], 1);
        perm[r] = (unsigned short)i;
    }
    __syncthreads();

    // pass 3: output-ordered write; e recovered from perm; pseudo read +
    // kb/frac quantize here (pseudo stream touched exactly once)
    for (int o = threadIdx.x; o < cnt; o += PTHR) {
        int i = perm[o];
        unsigned ux = (unsigned)stage[i];
        int e  = e0 + i;
        int sidx = ux & 0xFFFF;
        int nl   = (ux >> 16) & (BKT - 1);
        int b    = ux >> 22;
        float p0 = pseudo[3 * e + 0] * 4.f;
        float p1 = pseudo[3 * e + 1] * 4.f;
        float p2 = pseudo[3 * e + 2] * 4.f;
        int i0 = min(max((int)floorf(p0), 0), 3);
        int i1 = min(max((int)floorf(p1), 0), 3);
        int i2 = min(max((int)floorf(p2), 0), 3);
        float f0 = p0 - (float)i0, f1 = p1 - (float)i1, f2 = p2 - (float)i2;
        int kb = i0 + 5 * i1 + 25 * i2;
        int q0 = min((int)(f0 * 65536.f), 65535);
        int q1 = min((int)(f1 * 65536.f), 65535);
        int q2 = min((int)(f2 * 65536.f), 65535);
        int g = s_gmo[b] + o;
        if (g < (b + 1) * CAP) {             // memory-safety clamp
            pay8[g]  = make_int2(sidx | (kb << 16) | (nl << 23), q0 | (q1 << 16));
            payf2[g] = (unsigned short)q2;
        }
    }
}

// Layer 1 (R12/R15-proven structure): stage bucket in LDS, counting-sort perm,
// persist sorted payload + per-node [start,end); 8 lanes per node, 8 channel
// accumulators, b128 fp32 weight reads, butterfly; h written as f16 (halves
// layer2's dominant per-edge h-gather L2 traffic).
__global__ __launch_bounds__(512) void layer1_fused(
    int2* __restrict__ pay8, unsigned short* __restrict__ payf2,
    const int* __restrict__ cursor,
    const float* __restrict__ x, const float* __restrict__ W1,
    const float* __restrict__ root1, const float* __restrict__ bias1,
    __half* __restrict__ h, int* __restrict__ ns, int* __restrict__ ne, int N)
{
    __shared__ float sW[NK * WS];            // ~5.9 KB
    __shared__ int2 stage[CAP];              // 20.5 KB
    __shared__ unsigned short stf2[CAP];     // 5.1 KB
    __shared__ unsigned short perm[CAP];     // 5.1 KB
    __shared__ int hist[BKT];
    __shared__ int off[BKT + 1];
    __shared__ int cur[BKT];

    for (int i = threadIdx.x; i < NK * HID; i += 512)
        sW[(i >> 3) * WS + (i & 7)] = W1[i];
    if (threadIdx.x < BKT) hist[threadIdx.x] = 0;
    __syncthreads();

    int bkt  = blockIdx.x;
    int base = bkt * CAP;
    int cnt  = min(cursor[bkt] - base, CAP);

    for (int i = threadIdx.x; i < cnt; i += 512) {
        int2 pl = pay8[base + i];
        stage[i] = pl;
        stf2[i]  = payf2[base + i];
        atomicAdd(&hist[(pl.x >> 23) & (BKT - 1)], 1);
    }
    __syncthreads();

    if (threadIdx.x < BKT) {                 // wave-0 scan -> node offsets
        int v = hist[threadIdx.x];
        int incl = v;
        for (int d = 1; d < BKT; d <<= 1) {
            int u = __shfl_up(incl, d, 64);
            if (threadIdx.x >= d) incl += u;
        }
        off[threadIdx.x + 1] = incl;
        if (threadIdx.x == 0) off[0] = 0;
        cur[threadIdx.x] = incl - v;
    }
    __syncthreads();

    for (int i = threadIdx.x; i < cnt; i += 512) {
        int nl = (stage[i].x >> 23) & (BKT - 1);
        int pos = atomicAdd(&cur[nl], 1);
        perm[pos] = (unsigned short)i;
    }
    __syncthreads();

    // persist sorted payload (coalesced) + per-node bounds for layer2
    for (int i = threadIdx.x; i < cnt; i += 512) {
        int pi = perm[i];
        pay8[base + i]  = stage[pi];
        payf2[base + i] = stf2[pi];
    }
    if (threadIdx.x < BKT) {
        int n = (bkt << BSH) + threadIdx.x;
        if (n < N) {
            ns[n] = base + off[threadIdx.x];
            ne[n] = base + off[threadIdx.x + 1];
        }
    }

    int nl = threadIdx.x >> 3;               // 64 nodes x 8 lanes
    int j  = threadIdx.x & 7;
    int s = off[nl], e = off[nl + 1];

    float4 aclo = make_float4(0.f, 0.f, 0.f, 0.f);
    float4 achi = make_float4(0.f, 0.f, 0.f, 0.f);

    for (int i = s + j; i < e; i += 8) {
        int pi = perm[i];
        int2 pl = stage[pi];
        int packed = pl.x;
        float f0 = dq(pl.y & 0xFFFF);
        float f1 = dq((int)((unsigned)pl.y >> 16));
        float f2 = dq(stf2[pi]);
        int sidx = packed & 0xFFFF;
        int kb   = (packed >> 16) & 0x7F;
        float xj = x[sidx];
#pragma unroll
        for (int b = 0; b < 8; ++b) {
            int kidx = kb + (b & 1) + ((b >> 1) & 1) * 5 + ((b >> 2) & 1) * 25;
            float basis = ((b & 1) ? f0 : 1.f - f0)
                        * ((b & 2) ? f1 : 1.f - f1)
                        * ((b & 4) ? f2 : 1.f - f2);
            float w = xj * basis;
            float4 wlo = *(const float4*)&sW[kidx * WS];
            float4 whi = *(const float4*)&sW[kidx * WS + 4];
            aclo.x += w * wlo.x; aclo.y += w * wlo.y;
            aclo.z += w * wlo.z; aclo.w += w * wlo.w;
            achi.x += w * whi.x; achi.y += w * whi.y;
            achi.z += w * whi.z; achi.w += w * whi.w;
        }
    }

    float acc[HID] = {aclo.x, aclo.y, aclo.z, aclo.w, achi.x, achi.y, achi.z, achi.w};
#pragma unroll
    for (int m = 1; m < 8; m <<= 1)
#pragma unroll
        for (int o = 0; o < HID; ++o)
            acc[o] += __shfl_xor(acc[o], m, 64);

    int n = (bkt << BSH) + nl;
    if (n < N) {
        float v = acc[j] + x[n] * root1[j] + bias1[j];
        h[(size_t)n * HID + j] = __float2half(eluf(v));  // 8 lanes: 16B line
    }
}

// Layer 2 (R15 structure, f16 h): sort-free, stage-free; 8 lanes per node
// stream the node's sorted contiguous run; h-gather is ONE uint4 (16B =
// all 8 halves) per edge.
__global__ __launch_bounds__(256) void layer2_csr(
    const int2* __restrict__ pay8, const unsigned short* __restrict__ payf2,
    const int* __restrict__ ns, const int* __restrict__ ne,
    const __half* __restrict__ h, const float* __restrict__ W2,
    const float* __restrict__ root2, const float* __restrict__ bias2,
    float* __restrict__ out, int N)
{
    __shared__ float sW[NK * WS];
    for (int i = threadIdx.x; i < NK * HID; i += 256)
        sW[(i >> 3) * WS + (i & 7)] = W2[i];
    __syncthreads();

    int n = blockIdx.x * 32 + (threadIdx.x >> 3);
    int j = threadIdx.x & 7;
    int s = 0, e = 0;
    if (n < N) { s = ns[n]; e = ne[n]; }

    float msg = 0.f;
    for (int i = s + j; i < e; i += 8) {
        int2 pl = pay8[i];
        int packed = pl.x;
        float f0 = dq(pl.y & 0xFFFF);
        float f1 = dq((int)((unsigned)pl.y >> 16));
        float f2 = dq(payf2[i]);
        int sidx = packed & 0xFFFF;
        int kb   = (packed >> 16) & 0x7F;
        uint4 hw = *(const uint4*)(h + (size_t)sidx * HID);  // 16B: 8 halves
        float2 h01 = __half22float2(*(__half2*)&hw.x);
        float2 h23 = __half22float2(*(__half2*)&hw.y);
        float2 h45 = __half22float2(*(__half2*)&hw.z);
        float2 h67 = __half22float2(*(__half2*)&hw.w);
#pragma unroll
        for (int b = 0; b < 8; ++b) {
            int kidx = kb + (b & 1) + ((b >> 1) & 1) * 5 + ((b >> 2) & 1) * 25;
            float basis = ((b & 1) ? f0 : 1.f - f0)
                        * ((b & 2) ? f1 : 1.f - f1)
                        * ((b & 4) ? f2 : 1.f - f2);
            float4 wlo = *(const float4*)&sW[kidx * WS];
            float4 whi = *(const float4*)&sW[kidx * WS + 4];
            float dot = h01.x * wlo.x + h01.y * wlo.y + h23.x * wlo.z + h23.y * wlo.w
                      + h45.x * whi.x + h45.y * whi.y + h67.x * whi.z + h67.y * whi.w;
            msg += basis * dot;
        }
    }

    if (n < N) msg += __half2float(h[(size_t)n * HID + j]) * root2[j];

#pragma unroll
    for (int m = 1; m < 8; m <<= 1)
        msg += __shfl_xor(msg, m, 64);

    if (j == 0 && n < N)
        out[n] = eluf(msg + bias2[0]);
}

// ======================= fallback (atomic) path =======================

__global__ __launch_bounds__(256) void spline_edge1(
    const int* __restrict__ src, const int* __restrict__ dst,
    const float* __restrict__ pseudo, const float* __restrict__ x,
    const float* __restrict__ W1, float* __restrict__ hacc, int E)
{
    __shared__ float sW[HID * NK];
    for (int i = threadIdx.x; i < HID * NK; i += blockDim.x) {
        int k = i >> 3, o = i & 7;
        sW[o * NK + k] = W1[i];
    }
    __syncthreads();
    int e = blockIdx.x * blockDim.x + threadIdx.x;
    if (e >= E) return;
    float p0 = pseudo[3 * e + 0] * 4.f, p1 = pseudo[3 * e + 1] * 4.f, p2 = pseudo[3 * e + 2] * 4.f;
    int i0 = min(max((int)floorf(p0), 0), 3);
    int i1 = min(max((int)floorf(p1), 0), 3);
    int i2 = min(max((int)floorf(p2), 0), 3);
    float f0 = p0 - i0, f1 = p1 - i1, f2 = p2 - i2;
    int kbase = i0 + 5 * i1 + 25 * i2;
    float xj = x[src[e]];
    float acc[HID];
#pragma unroll
    for (int o = 0; o < HID; ++o) acc[o] = 0.f;
#pragma unroll
    for (int b = 0; b < 8; ++b) {
        int kidx = kbase + (b & 1) + ((b >> 1) & 1) * 5 + ((b >> 2) & 1) * 25;
        float basis = ((b & 1) ? f0 : 1.f - f0) * ((b & 2) ? f1 : 1.f - f1) * ((b & 4) ? f2 : 1.f - f2);
#pragma unroll
        for (int o = 0; o < HID; ++o) acc[o] += basis * sW[o * NK + kidx];
    }
    float* hp = hacc + (size_t)dst[e] * HID;
#pragma unroll
    for (int o = 0; o < HID; ++o) atomicAdd(hp + o, xj * acc[o]);
}

__global__ __launch_bounds__(256) void node1(
    float* __restrict__ h, const float* __restrict__ x,
    const float* __restrict__ root1, const float* __restrict__ bias1, int N)
{
    int t = blockIdx.x * blockDim.x + threadIdx.x;
    if (t >= N * HID) return;
    int n = t >> 3, o = t & 7;
    h[t] = eluf(h[t] + x[n] * root1[o] + bias1[o]);
}

__global__ __launch_bounds__(256) void spline_edge2(
    const int* __restrict__ src, const int* __restrict__ dst,
    const float* __restrict__ pseudo, const float* __restrict__ h,
    const float* __restrict__ W2, float* __restrict__ oacc, int E)
{
    __shared__ float sW[HID * NK];
    for (int idx = threadIdx.x; idx < HID * NK; idx += blockDim.x) {
        int k = idx >> 3, i = idx & 7;
        sW[i * NK + k] = W2[idx];
    }
    __syncthreads();
    int e = blockIdx.x * blockDim.x + threadIdx.x;
    if (e >= E) return;
    float p0 = pseudo[3 * e + 0] * 4.f, p1 = pseudo[3 * e + 1] * 4.f, p2 = pseudo[3 * e + 2] * 4.f;
    int i0 = min(max((int)floorf(p0), 0), 3);
    int i1 = min(max((int)floorf(p1), 0), 3);
    int i2 = min(max((int)floorf(p2), 0), 3);
    float f0 = p0 - i0, f1 = p1 - i1, f2 = p2 - i2;
    int kbase = i0 + 5 * i1 + 25 * i2;
    const float4* hp4 = (const float4*)(h + (size_t)src[e] * HID);
    float4 ha = hp4[0], hb = hp4[1];
    float hj[HID] = {ha.x, ha.y, ha.z, ha.w, hb.x, hb.y, hb.z, hb.w};
    float msg = 0.f;
#pragma unroll
    for (int b = 0; b < 8; ++b) {
        int kidx = kbase + (b & 1) + ((b >> 1) & 1) * 5 + ((b >> 2) & 1) * 25;
        float basis = ((b & 1) ? f0 : 1.f - f0) * ((b & 2) ? f1 : 1.f - f1) * ((b & 4) ? f2 : 1.f - f2);
        float dot = 0.f;
#pragma unroll
        for (int i = 0; i < HID; ++i) dot += hj[i] * sW[i * NK + kidx];
        msg += basis * dot;
    }
    atomicAdd(&oacc[dst[e]], msg);
}

__global__ __launch_bounds__(256) void node2(
    const float* __restrict__ oacc, const float* __restrict__ h,
    const float* __restrict__ root2, const float* __restrict__ bias2,
    float* __restrict__ out, int N)
{
    int n = blockIdx.x * blockDim.x + threadIdx.x;
    if (n >= N) return;
    float v = oacc[n] + bias2[0];
#pragma unroll
    for (int i = 0; i < HID; ++i) v += h[(size_t)n * HID + i] * root2[i];
    out[n] = eluf(v);
}

// ======================= launch =======================

extern "C" void kernel_launch(void* const* d_in, const int* in_sizes, int n_in,
                              void* d_out, int out_size, void* d_ws, size_t ws_size,
                              hipStream_t stream) {
    const float* x      = (const float*)d_in[0];
    const int*   ei     = (const int*)d_in[1];
    const float* pseudo = (const float*)d_in[2];
    const float* W1     = (const float*)d_in[3];
    const float* root1  = (const float*)d_in[4];
    const float* bias1  = (const float*)d_in[5];
    const float* W2     = (const float*)d_in[6];
    const float* root2  = (const float*)d_in[7];
    const float* bias2  = (const float*)d_in[8];

    int N = in_sizes[0];
    int E = in_sizes[1] / 2;
    const int* src = ei;
    const int* dst = ei + E;

    int NB = (N + BKT - 1) >> BSH;
    size_t pay8_bytes  = (size_t)NB * CAP * sizeof(int2);
    size_t payf2_bytes = (size_t)NB * CAP * sizeof(unsigned short);
    size_t h_bytes     = ((size_t)N * HID * sizeof(__half) + 15) & ~(size_t)15;
    size_t cursor_bytes = (size_t)NB * sizeof(int);
    size_t nsne_bytes  = (size_t)N * sizeof(int);
    size_t need = pay8_bytes + payf2_bytes + h_bytes + cursor_bytes + 2 * nsne_bytes + 64;

    if (NB <= MAXNB && N <= 65536 && E < (1 << 24) && ws_size >= need) {
        char* p = (char*)d_ws;
        int2*  pay8   = (int2*)p;                  p += pay8_bytes;
        unsigned short* payf2 = (unsigned short*)p; p += payf2_bytes;
        __half* h     = (__half*)p;                p += h_bytes;
        int*   cursor = (int*)p;                   p += cursor_bytes;
        int*   ns     = (int*)p;                   p += nsne_bytes;
        int*   ne     = (int*)p;

        init_cursor<<<(NB + 255) / 256, 256, 0, stream>>>(cursor, NB);
        int pblocks = (E + CHUNK - 1) / CHUNK;
        partition_edges<<<pblocks, PTHR, 0, stream>>>(src, dst, pseudo, cursor, pay8, payf2, E, NB);
        layer1_fused<<<NB, 512, 0, stream>>>(pay8, payf2, cursor, x, W1, root1, bias1, h, ns, ne, N);
        layer2_csr<<<(N + 31) / 32, 256, 0, stream>>>(pay8, payf2, ns, ne, h, W2, root2, bias2, (float*)d_out, N);
    } else {
        float* h    = (float*)d_ws;
        float* oacc = h + (size_t)N * HID;
        hipMemsetAsync(d_ws, 0, (size_t)(N * HID + N) * sizeof(float), stream);
        int eg = (E + 255) / 256;
        spline_edge1<<<eg, 256, 0, stream>>>(src, dst, pseudo, x, W1, h, E);
        node1<<<(N * HID + 255) / 256, 256, 0, stream>>>(h, x, root1, bias1, N);
        spline_edge2<<<eg, 256, 0, stream>>>(src, dst, pseudo, h, W2, oacc, E);
        node2<<<(N + 255) / 256, 256, 0, stream>>>(oacc, h, root2, bias2, (float*)d_out, N);
    }
}